// Round 4
// baseline (334.041 us; speedup 1.0000x reference)
//
#include <hip/hip_runtime.h>

#define DEV __device__ __forceinline__

typedef __attribute__((ext_vector_type(8))) short bf16x8;
typedef __attribute__((ext_vector_type(4))) float f32x4;

constexpr int Nn = 4096, Dd = 256, Kk = 128;
constexpr int RT = 128;     // rows per row-tile
constexpr int TILES = 4;    // row-tiles per block (512 rows)
constexpr int CHUNKS = 8;   // blocks per batch; grid = 32*8 = 256

DEV unsigned short f2bf(float f) {
  unsigned int u = __builtin_bit_cast(unsigned int, f);
  u += 0x7FFFu + ((u >> 16) & 1u);          // RNE; inputs are finite
  return (unsigned short)(u >> 16);
}
DEV float bf2f(unsigned short h) {
  unsigned int u = (unsigned int)h << 16;
  return __builtin_bit_cast(float, u);
}

// 256B LDS rows (128 bf16). XOR-swizzle bits 4-6 by h(row)=(row&7)^(((row>>3)&3)<<1):
// scalar b16 scatter writes and b128 fragment reads both stay <=2-way (free).
// Note h(row+32)==h(row), so store addresses are invariant mod 8192B steps.
DEV unsigned lds_addr(unsigned row, unsigned byteInRow) {
  unsigned h = (row & 7u) ^ (((row >> 3) & 3u) << 1);
  return row * 256u + (byteInRow ^ (h << 4));
}

__global__ void enc_prep(const float* __restrict__ cw, const float* __restrict__ sc,
                         unsigned short* __restrict__ cbf, float2* __restrict__ tab) {
  int k = blockIdx.x, l = threadIdx.x;          // 128 blocks x 64 threads
  float4 u = *(const float4*)(cw + k * Dd + l * 4);
  float s2 = u.x * u.x + u.y * u.y + u.z * u.z + u.w * u.w;
  #pragma unroll
  for (int o = 1; o < 64; o <<= 1) s2 += __shfl_xor(s2, o);
  unsigned short* dst = cbf + k * Dd + l * 4;
  dst[0] = f2bf(u.x); dst[1] = f2bf(u.y); dst[2] = f2bf(u.z); dst[3] = f2bf(u.w);
  if (l == 0) { float s = sc[k]; tab[k] = make_float2(s * s2, 2.0f * s); }
}

// PMODE: 0 = fp32 partials to Ep, 1 = bf16 partials to Ep, 2 = atomicAdd to out
template<int PMODE>
DEV void enc_impl(const float* __restrict__ x, const unsigned short* __restrict__ cbf,
                  const float2* __restrict__ tab, const float* __restrict__ cwf,
                  char* __restrict__ Ep, float* __restrict__ out) {
  // LDS: xT (256 x 128 bf16, swz) = 64KB ; W (128 x 128 bf16, swz) = 32KB ; misc 2.5KB
  __shared__ __align__(16) char smem[98304];
  __shared__ float WsumL[Kk];
  __shared__ float2 tabL[Kk];
  __shared__ float hs[2][RT];
  char* Wb = smem + 65536;

  const int tid = threadIdx.x;
  const int w  = tid >> 6;           // wave 0..15
  const int l  = tid & 63;
  const int g  = l >> 4;             // 16-lane group 0..3
  const int ln = l & 15;
  const int rgrp = w >> 1, h = w & 1;  // phase-1: row group 0..7, cw-half 0..1
  const int wr = w >> 2, wc = w & 3;   // phase-2 wave grid 4x4 over E(128 x 256)
  const int b = blockIdx.x >> 3, chunk = blockIdx.x & 7;
  const int row = rgrp * 16 + ln;      // this lane's n-row within the tile

  const float* xb = x + ((size_t)b * Nn + (size_t)chunk * (TILES * RT)) * Dd;

  if (tid < Kk) { WsumL[tid] = 0.0f; tabL[tid] = tab[tid]; }
  __syncthreads();

  f32x4 acc[2][4];
  const f32x4 zero4 = {0.f, 0.f, 0.f, 0.f};
  #pragma unroll
  for (int mi = 0; mi < 2; ++mi)
    #pragma unroll
    for (int ni = 0; ni < 4; ++ni) acc[mi][ni] = zero4;

  const unsigned colb = (unsigned)row * 2u;  // this lane's n-column (bytes)
  // hoisted xT store addresses (rows g*8+i); +ks*8192 folds into ds_write offset imm
  unsigned a_st[8];
  #pragma unroll
  for (int i = 0; i < 8; ++i) a_st[i] = lds_addr((unsigned)(g * 8 + i), colb);

  for (int t = 0; t < TILES; ++t) {
    // -------- Phase 1: S^T = mfma(c_half, x); wave pair splits the 128 cw
    const float* xrow = xb + ((size_t)t * RT + row) * Dd;
    f32x4 s1[4];
    #pragma unroll
    for (int f = 0; f < 4; ++f) s1[f] = zero4;
    float x2p = 0.f;

    #pragma unroll
    for (int ks = 0; ks < 8; ++ks) {
      const int d0 = ks * 32 + g * 8;
      float4 u0 = *(const float4*)(xrow + d0);
      float4 u1 = *(const float4*)(xrow + d0 + 4);
      x2p += u0.x*u0.x + u0.y*u0.y + u0.z*u0.z + u0.w*u0.w
           + u1.x*u1.x + u1.y*u1.y + u1.z*u1.z + u1.w*u1.w;
      unsigned short q0 = f2bf(u0.x), q1 = f2bf(u0.y), q2 = f2bf(u0.z), q3 = f2bf(u0.w);
      unsigned short q4 = f2bf(u1.x), q5 = f2bf(u1.y), q6 = f2bf(u1.z), q7 = f2bf(u1.w);
      bf16x8 xv;
      xv[0] = (short)q0; xv[1] = (short)q1; xv[2] = (short)q2; xv[3] = (short)q3;
      xv[4] = (short)q4; xv[5] = (short)q5; xv[6] = (short)q6; xv[7] = (short)q7;
      if (h == 0) {   // half 0 stages xT; half 1's x loads hit L2 (same tile, same time)
        *(unsigned short*)(smem + a_st[0] + ks * 8192) = q0;
        *(unsigned short*)(smem + a_st[1] + ks * 8192) = q1;
        *(unsigned short*)(smem + a_st[2] + ks * 8192) = q2;
        *(unsigned short*)(smem + a_st[3] + ks * 8192) = q3;
        *(unsigned short*)(smem + a_st[4] + ks * 8192) = q4;
        *(unsigned short*)(smem + a_st[5] + ks * 8192) = q5;
        *(unsigned short*)(smem + a_st[6] + ks * 8192) = q6;
        *(unsigned short*)(smem + a_st[7] + ks * 8192) = q7;
      }
      #pragma unroll
      for (int f = 0; f < 4; ++f) {
        bf16x8 a = *(const bf16x8*)(cbf + (h * 64 + f * 16 + ln) * Dd + d0);
        s1[f] = __builtin_amdgcn_mfma_f32_16x16x32_bf16(a, xv, s1[f], 0, 0, 0);
      }
    }

    // -------- softmax over K: lane-local 16 vals + 2 shuffles + cross-half LDS sum
    x2p += __shfl_xor(x2p, 16); x2p += __shfl_xor(x2p, 32);
    const float hx2 = 0.5f * x2p;
    float ssum = 0.f;
    #pragma unroll
    for (int f = 0; f < 4; ++f) {
      #pragma unroll
      for (int r = 0; r < 4; ++r) {
        const float2 ab = tabL[h * 64 + f * 16 + g * 4 + r];     // (alpha, beta)
        const float ev = __expf(ab.x + ab.y * (hx2 - s1[f][r]));
        s1[f][r] = ev;
        ssum += ev;
      }
    }
    ssum += __shfl_xor(ssum, 16); ssum += __shfl_xor(ssum, 32);
    if (g == 0) hs[h][row] = ssum;
    __syncthreads();   // (1) hs + xT complete

    const float rinv = 1.0f / (hs[0][row] + hs[1][row]);
    #pragma unroll
    for (int f = 0; f < 4; ++f) {
      #pragma unroll
      for (int r = 0; r < 4; ++r) {
        const int cwi = h * 64 + f * 16 + g * 4 + r;
        const float wv = s1[f][r] * rinv;
        *(unsigned short*)(Wb + lds_addr((unsigned)cwi, colb)) = f2bf(wv);
        float tsum = wv;                                // sum over this wave's 16 rows
        tsum += __shfl_xor(tsum, 1);
        tsum += __shfl_xor(tsum, 2);
        tsum += __shfl_xor(tsum, 4);
        tsum += __shfl_xor(tsum, 8);
        if (ln == 0) atomicAdd(&WsumL[cwi], tsum);
      }
    }
    __syncthreads();   // (2) W complete

    // -------- Phase 2: E(128x256) += W^T-frags x xT-frags, 4x4 wave grid
    #pragma unroll
    for (int ks2 = 0; ks2 < 4; ++ks2) {
      const unsigned nb = (unsigned)(ks2 * 32 + g * 8) * 2u;
      bf16x8 af[2], bg[4];
      #pragma unroll
      for (int mi = 0; mi < 2; ++mi)
        af[mi] = *(const bf16x8*)(Wb + lds_addr((unsigned)(wr * 32 + mi * 16 + ln), nb));
      #pragma unroll
      for (int ni = 0; ni < 4; ++ni)
        bg[ni] = *(const bf16x8*)(smem + lds_addr((unsigned)(wc * 64 + ni * 16 + ln), nb));
      #pragma unroll
      for (int mi = 0; mi < 2; ++mi)
        #pragma unroll
        for (int ni = 0; ni < 4; ++ni)
          acc[mi][ni] = __builtin_amdgcn_mfma_f32_16x16x32_bf16(af[mi], bg[ni], acc[mi][ni], 0, 0, 0);
    }
    __syncthreads();   // (3) safe to overwrite xT/W/hs next tile
  }

  // -------- epilogue: Epart[k,d] = acc - Wsum_chunk * c
  #pragma unroll
  for (int mi = 0; mi < 2; ++mi) {
    #pragma unroll
    for (int r = 0; r < 4; ++r) {
      const int cwi = wr * 32 + mi * 16 + g * 4 + r;
      const float wsv = WsumL[cwi];
      #pragma unroll
      for (int ni = 0; ni < 4; ++ni) {
        const int d = wc * 64 + ni * 16 + ln;
        const float v = acc[mi][ni][r] - wsv * cwf[cwi * Dd + d];
        if (PMODE == 0) {
          ((float*)Ep)[(size_t)blockIdx.x * (Kk * Dd) + cwi * Dd + d] = v;
        } else if (PMODE == 1) {
          ((unsigned short*)Ep)[(size_t)blockIdx.x * (Kk * Dd) + cwi * Dd + d] = f2bf(v);
        } else {
          atomicAdd(out + (size_t)b * (Kk * Dd) + cwi * Dd + d, v);
        }
      }
    }
  }
}

// Distinct names so rocprof reveals which tier ran.
__global__ __launch_bounds__(1024, 4) void enc_main_f32(
    const float* __restrict__ x, const unsigned short* __restrict__ cbf,
    const float2* __restrict__ tab, const float* __restrict__ cwf,
    char* __restrict__ Ep, float* __restrict__ out) {
  enc_impl<0>(x, cbf, tab, cwf, Ep, out);
}
__global__ __launch_bounds__(1024, 4) void enc_main_b16(
    const float* __restrict__ x, const unsigned short* __restrict__ cbf,
    const float2* __restrict__ tab, const float* __restrict__ cwf,
    char* __restrict__ Ep, float* __restrict__ out) {
  enc_impl<1>(x, cbf, tab, cwf, Ep, out);
}
__global__ __launch_bounds__(1024, 4) void enc_main_atm(
    const float* __restrict__ x, const unsigned short* __restrict__ cbf,
    const float2* __restrict__ tab, const float* __restrict__ cwf,
    char* __restrict__ Ep, float* __restrict__ out) {
  enc_impl<2>(x, cbf, tab, cwf, Ep, out);
}

__global__ void enc_reduce_f32(const float* __restrict__ Ep, float* __restrict__ out) {
  const size_t i = ((size_t)blockIdx.x * 256 + threadIdx.x) * 4;   // float4 per thread
  const int b   = (int)(i / (Kk * Dd));
  const int rem = (int)(i % (Kk * Dd));
  const float* p = Ep + (size_t)b * CHUNKS * (Kk * Dd) + rem;
  float4 s = *(const float4*)p;
  #pragma unroll
  for (int c = 1; c < CHUNKS; ++c) {
    float4 v = *(const float4*)(p + (size_t)c * (Kk * Dd));
    s.x += v.x; s.y += v.y; s.z += v.z; s.w += v.w;
  }
  *(float4*)(out + i) = s;
}

__global__ void enc_reduce_bf16(const unsigned short* __restrict__ Ep, float* __restrict__ out) {
  const size_t i = ((size_t)blockIdx.x * 256 + threadIdx.x) * 4;
  const int b   = (int)(i / (Kk * Dd));
  const int rem = (int)(i % (Kk * Dd));
  const unsigned short* p = Ep + (size_t)b * CHUNKS * (Kk * Dd) + rem;
  float sx = 0.f, sy = 0.f, sz = 0.f, sw = 0.f;
  #pragma unroll
  for (int c = 0; c < CHUNKS; ++c) {
    ushort4 v = *(const ushort4*)(p + (size_t)c * (Kk * Dd));
    sx += bf2f(v.x); sy += bf2f(v.y); sz += bf2f(v.z); sw += bf2f(v.w);
  }
  float4 s = make_float4(sx, sy, sz, sw);
  *(float4*)(out + i) = s;
}

extern "C" void kernel_launch(void* const* d_in, const int* in_sizes, int n_in,
                              void* d_out, int out_size, void* d_ws, size_t ws_size,
                              hipStream_t stream) {
  const float* x  = (const float*)d_in[0];   // (32, 4096, 256)
  const float* cw = (const float*)d_in[1];   // (128, 256)
  const float* sc = (const float*)d_in[2];   // (128,)
  float* out = (float*)d_out;                // (32, 128, 256)

  unsigned short* cbf = (unsigned short*)d_ws;                    // 64KB bf16 codewords
  float2* tab = (float2*)((char*)d_ws + 65536);                   // 1KB (alpha, beta)
  char*   Ep  = (char*)d_ws + 66560;                              // chunk partials
  const size_t KD = (size_t)Kk * Dd;
  const size_t needF32 = 66560 + (size_t)32 * CHUNKS * KD * 4;    // ~33.6 MB
  const size_t needB16 = 66560 + (size_t)32 * CHUNKS * KD * 2;    // ~16.8 MB

  enc_prep<<<dim3(Kk), dim3(64), 0, stream>>>(cw, sc, cbf, tab);

  const int rgrid = (int)((32 * KD) / (256 * 4));                 // 1024 blocks
  if (ws_size >= needF32) {
    enc_main_f32<<<dim3(256), dim3(1024), 0, stream>>>(x, cbf, tab, cw, Ep, out);
    enc_reduce_f32<<<dim3(rgrid), dim3(256), 0, stream>>>((const float*)Ep, out);
  } else if (ws_size >= needB16) {
    enc_main_b16<<<dim3(256), dim3(1024), 0, stream>>>(x, cbf, tab, cw, Ep, out);
    enc_reduce_bf16<<<dim3(rgrid), dim3(256), 0, stream>>>((const unsigned short*)Ep, out);
  } else {
    hipMemsetAsync(d_out, 0, (size_t)out_size * sizeof(float), stream);
    enc_main_atm<<<dim3(256), dim3(1024), 0, stream>>>(x, cbf, tab, cw, nullptr, out);
  }
}

// Round 5
// 203.597 us; speedup vs baseline: 1.6407x; 1.6407x over previous
//
#include <hip/hip_runtime.h>

#define DEV __device__ __forceinline__

typedef __attribute__((ext_vector_type(8))) short bf16x8;
typedef __attribute__((ext_vector_type(4))) float f32x4;

constexpr int Nn = 4096, Dd = 256, Kk = 128;
constexpr int RT = 128;     // rows per row-tile
constexpr int TILES = 4;    // row-tiles per block (512 rows)
constexpr int CHUNKS = 8;   // blocks per batch; grid = 32*8 = 256

DEV unsigned short f2bf(float f) {
  unsigned int u = __builtin_bit_cast(unsigned int, f);
  u += 0x7FFFu + ((u >> 16) & 1u);          // RNE; inputs are finite
  return (unsigned short)(u >> 16);
}
DEV float bf2f(unsigned short h) {
  unsigned int u = (unsigned int)h << 16;
  return __builtin_bit_cast(float, u);
}

// 256B LDS rows (128 bf16). XOR-swizzle bits 4-6 by h(row)=(row&7)^(((row>>3)&3)<<1):
// scalar b16 scatter writes and b128 fragment reads both stay <=2-way (free).
// h(row+32)==h(row), so xT store addresses are invariant under +32-row steps.
DEV unsigned lds_addr(unsigned row, unsigned byteInRow) {
  unsigned h = (row & 7u) ^ (((row >> 3) & 3u) << 1);
  return row * 256u + (byteInRow ^ (h << 4));
}

__global__ void enc_prep(const float* __restrict__ cw, const float* __restrict__ sc,
                         unsigned short* __restrict__ cbf, float2* __restrict__ tab) {
  int k = blockIdx.x, l = threadIdx.x;          // 128 blocks x 64 threads
  float4 u = *(const float4*)(cw + k * Dd + l * 4);
  float s2 = u.x * u.x + u.y * u.y + u.z * u.z + u.w * u.w;
  #pragma unroll
  for (int o = 1; o < 64; o <<= 1) s2 += __shfl_xor(s2, o);
  unsigned short* dst = cbf + k * Dd + l * 4;
  dst[0] = f2bf(u.x); dst[1] = f2bf(u.y); dst[2] = f2bf(u.z); dst[3] = f2bf(u.w);
  if (l == 0) { float s = sc[k]; tab[k] = make_float2(s * s2, 2.0f * s); }
}

// PMODE: 0 = fp32 partials to Ep, 1 = bf16 partials to Ep, 2 = atomicAdd to out
template<int PMODE>
DEV void enc_impl(const float* __restrict__ x, const unsigned short* __restrict__ cbf,
                  const float2* __restrict__ tab, const float* __restrict__ cwf,
                  char* __restrict__ Ep, float* __restrict__ out) {
  // LDS: xT (256 x 128 bf16, swz) = 64KB ; W (128 x 128 bf16, swz) = 32KB ; misc 1.5KB
  __shared__ __align__(16) char smem[98304];
  __shared__ float WsumL[Kk];
  __shared__ float2 tabL[Kk];
  char* Wb = smem + 65536;

  const int tid = threadIdx.x;
  const int w  = tid >> 6;           // wave 0..7
  const int l  = tid & 63;
  const int g  = l >> 4;             // 16-lane group 0..3
  const int ln = l & 15;
  const int wr = w >> 2, wc = w & 3; // phase-2 wave grid 2x4 over E(128 x 256)
  const int b = blockIdx.x >> 3, chunk = blockIdx.x & 7;
  const int row = w * 16 + ln;       // this lane's n-row within the tile

  const float* xb = x + ((size_t)b * Nn + (size_t)chunk * (TILES * RT)) * Dd;

  if (tid < Kk) { WsumL[tid] = 0.0f; tabL[tid] = tab[tid]; }
  __syncthreads();

  f32x4 acc[4][4];
  const f32x4 zero4 = {0.f, 0.f, 0.f, 0.f};
  #pragma unroll
  for (int mi = 0; mi < 4; ++mi)
    #pragma unroll
    for (int ni = 0; ni < 4; ++ni) acc[mi][ni] = zero4;

  const unsigned colb = (unsigned)row * 2u;  // this lane's n-column (bytes)
  // hoisted xT store addresses (rows g*8+i); +ks*8192 folds into the offset imm
  unsigned a_st[8];
  #pragma unroll
  for (int i = 0; i < 8; ++i) a_st[i] = lds_addr((unsigned)(g * 8 + i), colb);

  for (int t = 0; t < TILES; ++t) {
    // -------- Phase 1: S^T = mfma(c, x); each wave owns 16 rows x all 128 cw
    const float* xrow = xb + ((size_t)t * RT + row) * Dd;
    f32x4 s1[8];
    #pragma unroll
    for (int f = 0; f < 8; ++f) s1[f] = zero4;
    float x2p = 0.f;

    #pragma unroll
    for (int ks = 0; ks < 8; ++ks) {
      const int d0 = ks * 32 + g * 8;
      float4 u0 = *(const float4*)(xrow + d0);
      float4 u1 = *(const float4*)(xrow + d0 + 4);
      x2p += u0.x*u0.x + u0.y*u0.y + u0.z*u0.z + u0.w*u0.w
           + u1.x*u1.x + u1.y*u1.y + u1.z*u1.z + u1.w*u1.w;
      unsigned short q0 = f2bf(u0.x), q1 = f2bf(u0.y), q2 = f2bf(u0.z), q3 = f2bf(u0.w);
      unsigned short q4 = f2bf(u1.x), q5 = f2bf(u1.y), q6 = f2bf(u1.z), q7 = f2bf(u1.w);
      bf16x8 xv;
      xv[0] = (short)q0; xv[1] = (short)q1; xv[2] = (short)q2; xv[3] = (short)q3;
      xv[4] = (short)q4; xv[5] = (short)q5; xv[6] = (short)q6; xv[7] = (short)q7;
      // single x read feeds both MFMA operand and transposed LDS stage
      *(unsigned short*)(smem + a_st[0] + ks * 8192) = q0;
      *(unsigned short*)(smem + a_st[1] + ks * 8192) = q1;
      *(unsigned short*)(smem + a_st[2] + ks * 8192) = q2;
      *(unsigned short*)(smem + a_st[3] + ks * 8192) = q3;
      *(unsigned short*)(smem + a_st[4] + ks * 8192) = q4;
      *(unsigned short*)(smem + a_st[5] + ks * 8192) = q5;
      *(unsigned short*)(smem + a_st[6] + ks * 8192) = q6;
      *(unsigned short*)(smem + a_st[7] + ks * 8192) = q7;
      #pragma unroll
      for (int f = 0; f < 8; ++f) {
        bf16x8 a = *(const bf16x8*)(cbf + (f * 16 + ln) * Dd + d0);
        s1[f] = __builtin_amdgcn_mfma_f32_16x16x32_bf16(a, xv, s1[f], 0, 0, 0);
      }
    }

    // -------- softmax over K (lane-local: 32 values + 2 shuffles)
    x2p += __shfl_xor(x2p, 16); x2p += __shfl_xor(x2p, 32);
    const float hx2 = 0.5f * x2p;
    float ssum = 0.f;
    #pragma unroll
    for (int f = 0; f < 8; ++f) {
      #pragma unroll
      for (int r = 0; r < 4; ++r) {
        const float2 ab = tabL[f * 16 + g * 4 + r];     // (alpha, beta)
        const float ev = __expf(ab.x + ab.y * (hx2 - s1[f][r]));
        s1[f][r] = ev;
        ssum += ev;
      }
    }
    ssum += __shfl_xor(ssum, 16); ssum += __shfl_xor(ssum, 32);
    const float rinv = 1.0f / ssum;

    #pragma unroll
    for (int f = 0; f < 8; ++f) {
      #pragma unroll
      for (int r = 0; r < 4; ++r) {
        const int cwi = f * 16 + g * 4 + r;
        const float wv = s1[f][r] * rinv;
        *(unsigned short*)(Wb + lds_addr((unsigned)cwi, colb)) = f2bf(wv);
        float tsum = wv;                                // sum over the wave's 16 rows
        tsum += __shfl_xor(tsum, 1);
        tsum += __shfl_xor(tsum, 2);
        tsum += __shfl_xor(tsum, 4);
        tsum += __shfl_xor(tsum, 8);
        if (ln == 0) atomicAdd(&WsumL[cwi], tsum);
      }
    }
    __syncthreads();   // xT + W complete

    // -------- Phase 2: E(128x256) += W^T-frags x xT-frags, 2x4 wave grid
    #pragma unroll
    for (int ks2 = 0; ks2 < 4; ++ks2) {
      const unsigned nb = (unsigned)(ks2 * 32 + g * 8) * 2u;
      bf16x8 af[4], bg[4];
      #pragma unroll
      for (int mi = 0; mi < 4; ++mi)
        af[mi] = *(const bf16x8*)(Wb + lds_addr((unsigned)(wr * 64 + mi * 16 + ln), nb));
      #pragma unroll
      for (int ni = 0; ni < 4; ++ni)
        bg[ni] = *(const bf16x8*)(smem + lds_addr((unsigned)(wc * 64 + ni * 16 + ln), nb));
      #pragma unroll
      for (int mi = 0; mi < 4; ++mi)
        #pragma unroll
        for (int ni = 0; ni < 4; ++ni)
          acc[mi][ni] = __builtin_amdgcn_mfma_f32_16x16x32_bf16(af[mi], bg[ni], acc[mi][ni], 0, 0, 0);
    }
    __syncthreads();   // before next tile overwrites xT/W
  }

  // -------- epilogue: Epart[k,d] = acc - Wsum_chunk * c
  #pragma unroll
  for (int mi = 0; mi < 4; ++mi) {
    #pragma unroll
    for (int r = 0; r < 4; ++r) {
      const int cwi = wr * 64 + mi * 16 + g * 4 + r;
      const float wsv = WsumL[cwi];
      #pragma unroll
      for (int ni = 0; ni < 4; ++ni) {
        const int d = wc * 64 + ni * 16 + ln;
        const float v = acc[mi][ni][r] - wsv * cwf[cwi * Dd + d];
        if (PMODE == 0) {
          ((float*)Ep)[(size_t)blockIdx.x * (Kk * Dd) + cwi * Dd + d] = v;
        } else if (PMODE == 1) {
          ((unsigned short*)Ep)[(size_t)blockIdx.x * (Kk * Dd) + cwi * Dd + d] = f2bf(v);
        } else {
          atomicAdd(out + (size_t)b * (Kk * Dd) + cwi * Dd + d, v);
        }
      }
    }
  }
}

// NOTE: __launch_bounds__ 2nd arg is min BLOCKS per CU (CUDA semantics).
// (512,2) capped the allocator at 128 VGPRs and spilled acc/s1 to scratch —
// that spill traffic was rounds 1-4's ~350us wall. (512,1) -> 256-VGPR cap.
__global__ __launch_bounds__(512, 1) void enc_main_f32(
    const float* __restrict__ x, const unsigned short* __restrict__ cbf,
    const float2* __restrict__ tab, const float* __restrict__ cwf,
    char* __restrict__ Ep, float* __restrict__ out) {
  enc_impl<0>(x, cbf, tab, cwf, Ep, out);
}
__global__ __launch_bounds__(512, 1) void enc_main_b16(
    const float* __restrict__ x, const unsigned short* __restrict__ cbf,
    const float2* __restrict__ tab, const float* __restrict__ cwf,
    char* __restrict__ Ep, float* __restrict__ out) {
  enc_impl<1>(x, cbf, tab, cwf, Ep, out);
}
__global__ __launch_bounds__(512, 1) void enc_main_atm(
    const float* __restrict__ x, const unsigned short* __restrict__ cbf,
    const float2* __restrict__ tab, const float* __restrict__ cwf,
    char* __restrict__ Ep, float* __restrict__ out) {
  enc_impl<2>(x, cbf, tab, cwf, nullptr, out);
}

__global__ void enc_reduce_f32(const float* __restrict__ Ep, float* __restrict__ out) {
  const size_t i = ((size_t)blockIdx.x * 256 + threadIdx.x) * 4;   // float4 per thread
  const int b   = (int)(i / (Kk * Dd));
  const int rem = (int)(i % (Kk * Dd));
  const float* p = Ep + (size_t)b * CHUNKS * (Kk * Dd) + rem;
  float4 s = *(const float4*)p;
  #pragma unroll
  for (int c = 1; c < CHUNKS; ++c) {
    float4 v = *(const float4*)(p + (size_t)c * (Kk * Dd));
    s.x += v.x; s.y += v.y; s.z += v.z; s.w += v.w;
  }
  *(float4*)(out + i) = s;
}

__global__ void enc_reduce_bf16(const unsigned short* __restrict__ Ep, float* __restrict__ out) {
  const size_t i = ((size_t)blockIdx.x * 256 + threadIdx.x) * 4;
  const int b   = (int)(i / (Kk * Dd));
  const int rem = (int)(i % (Kk * Dd));
  const unsigned short* p = Ep + (size_t)b * CHUNKS * (Kk * Dd) + rem;
  float sx = 0.f, sy = 0.f, sz = 0.f, sw = 0.f;
  #pragma unroll
  for (int c = 0; c < CHUNKS; ++c) {
    ushort4 v = *(const ushort4*)(p + (size_t)c * (Kk * Dd));
    sx += bf2f(v.x); sy += bf2f(v.y); sz += bf2f(v.z); sw += bf2f(v.w);
  }
  float4 s = make_float4(sx, sy, sz, sw);
  *(float4*)(out + i) = s;
}

extern "C" void kernel_launch(void* const* d_in, const int* in_sizes, int n_in,
                              void* d_out, int out_size, void* d_ws, size_t ws_size,
                              hipStream_t stream) {
  const float* x  = (const float*)d_in[0];   // (32, 4096, 256)
  const float* cw = (const float*)d_in[1];   // (128, 256)
  const float* sc = (const float*)d_in[2];   // (128,)
  float* out = (float*)d_out;                // (32, 128, 256)

  unsigned short* cbf = (unsigned short*)d_ws;                    // 64KB bf16 codewords
  float2* tab = (float2*)((char*)d_ws + 65536);                   // 1KB (alpha, beta)
  char*   Ep  = (char*)d_ws + 66560;                              // chunk partials
  const size_t KD = (size_t)Kk * Dd;
  const size_t needF32 = 66560 + (size_t)32 * CHUNKS * KD * 4;    // ~33.6 MB
  const size_t needB16 = 66560 + (size_t)32 * CHUNKS * KD * 2;    // ~16.8 MB

  enc_prep<<<dim3(Kk), dim3(64), 0, stream>>>(cw, sc, cbf, tab);

  const int rgrid = (int)((32 * KD) / (256 * 4));                 // 1024 blocks
  if (ws_size >= needF32) {
    enc_main_f32<<<dim3(256), dim3(512), 0, stream>>>(x, cbf, tab, cw, Ep, out);
    enc_reduce_f32<<<dim3(rgrid), dim3(256), 0, stream>>>((const float*)Ep, out);
  } else if (ws_size >= needB16) {
    enc_main_b16<<<dim3(256), dim3(512), 0, stream>>>(x, cbf, tab, cw, Ep, out);
    enc_reduce_bf16<<<dim3(rgrid), dim3(256), 0, stream>>>((const unsigned short*)Ep, out);
  } else {
    hipMemsetAsync(d_out, 0, (size_t)out_size * sizeof(float), stream);
    enc_main_atm<<<dim3(256), dim3(512), 0, stream>>>(x, cbf, tab, cw, nullptr, out);
  }
}